// Round 8
// baseline (673.707 us; speedup 1.0000x reference)
//
#include <hip/hip_runtime.h>
#include <hip/hip_bf16.h>

#define NN 8192
#define FIN 256
#define FOUT 64
#define L2E 1.4426950408889634f
#define PADK2 72      // LDS k-stride in shorts (64 data + 8 pad; R3-verified)
#define FDBOUND 64.0f // safe upper bound on max_j fd[j] (|fd|<~15 for this data;
                      // any bound works: softmax offset cancels in num/den)

typedef __attribute__((ext_vector_type(8))) short short8;
typedef __attribute__((ext_vector_type(4))) float f32x4;
typedef __attribute__((ext_vector_type(4))) int   iv4;

// Barrier with LDS-only drain: leaves vmcnt (global prefetch) in flight.
#define BAR() do { \
  __asm__ __volatile__("s_waitcnt lgkmcnt(0)" ::: "memory"); \
  __builtin_amdgcn_s_barrier(); \
  __asm__ __volatile__("" ::: "memory"); \
} while (0)

__device__ __forceinline__ unsigned short f2bf(float x){
  unsigned u = __float_as_uint(x);
  u += 0x7FFFu + ((u >> 16) & 1u);      // RTNE
  return (unsigned short)(u >> 16);
}

// spread4: deposit bit i of 8-bit x at bit 4i (verified: 0x02 -> 0x10).
__device__ __forceinline__ unsigned spread4(unsigned x){
  x &= 0xFFu;
  x = (x | (x << 12)) & 0x000F000Fu;
  x = (x | (x << 6))  & 0x03030303u;
  x = (x | (x << 3))  & 0x11111111u;
  return x;
}

// Convert one 1-KB adj group (256 j) to 8 mask words (R0-verified).
__device__ __forceinline__ void cv_process(iv4 d, int l,
                                           unsigned* __restrict__ mp, int g){
  unsigned n = (unsigned)(d.x != 0)        | ((unsigned)(d.y != 0) << 1)
             | ((unsigned)(d.z != 0) << 2) | ((unsigned)(d.w != 0) << 3);
  unsigned long long B0 = __ballot((n & 1u) != 0);
  unsigned long long B1 = __ballot((n & 2u) != 0);
  unsigned long long B2 = __ballot((n & 4u) != 0);
  unsigned long long B3 = __ballot((n & 8u) != 0);
  const int hi = l & 4, sh = (l & 3) * 8;
  unsigned b0 = (unsigned)((hi ? (B0 >> 32) : B0) >> sh);
  unsigned b1 = (unsigned)((hi ? (B1 >> 32) : B1) >> sh);
  unsigned b2 = (unsigned)((hi ? (B2 >> 32) : B2) >> sh);
  unsigned b3 = (unsigned)((hi ? (B3 >> 32) : B3) >> sh);
  unsigned word = spread4(b0) | (spread4(b1) << 1)
                | (spread4(b2) << 2) | (spread4(b3) << 3);
  if (l < 8) mp[g*8 + l] = word;
}

__device__ __forceinline__ void attn_math(unsigned mbits, f32x4 fv0, f32x4 fv1,
    short8 w0, short8 w1, short8 w2, short8 w3,
    float fsrL, float mL, f32x4* acc, float& s0, float& s1){
  const float fv[8] = {fv0[0],fv0[1],fv0[2],fv0[3], fv1[0],fv1[1],fv1[2],fv1[3]};
  float w[8];
  #pragma unroll
  for (int j = 0; j < 8; ++j){
    float x  = fsrL + fv[j];                      // log2 domain
    float tt = fmaxf(x, 0.2f*x);                  // leaky_relu (scale-invariant)
    float e  = __builtin_amdgcn_exp2f(tt - mL);   // v_exp_f32
    w[j] = (mbits & (1u << j)) ? e : 0.0f;
  }
  s0 += (w[0]+w[2]) + (w[4]+w[6]);
  s1 += (w[1]+w[3]) + (w[5]+w[7]);
  short8 af;
  __hip_bfloat162* afp = (__hip_bfloat162*)&af;
  #pragma unroll
  for (int j = 0; j < 4; ++j)
    afp[j] = __float22bfloat162_rn(make_float2(w[2*j], w[2*j+1]));
  acc[0] = __builtin_amdgcn_mfma_f32_16x16x32_bf16(af, w0, acc[0], 0,0,0);
  acc[1] = __builtin_amdgcn_mfma_f32_16x16x32_bf16(af, w1, acc[1], 0,0,0);
  acc[2] = __builtin_amdgcn_mfma_f32_16x16x32_bf16(af, w2, acc[2], 0,0,0);
  acc[3] = __builtin_amdgcn_mfma_f32_16x16x32_bf16(af, w3, acc[3], 0,0,0);
}

// ---- k_mega: matmul (bid<1024) + converter/attn interleaved 4:1.
// attn blocks spin on device-scope counters, then run R3's verified body;
// BW-bound converter overlaps latency-bound attention on the same device.
// Deadlock-free: 512 attn blocks < 1024 resident slots (4 blocks/CU).
__global__ __launch_bounds__(256, 4) void k_mega(const float* __restrict__ h,
    const float* __restrict__ W, const float* __restrict__ a,
    const int* __restrict__ adj, unsigned short* __restrict__ WhT,
    float* __restrict__ fs, float* __restrict__ fd,
    unsigned* __restrict__ mask, float* __restrict__ acc_out,
    float* __restrict__ s_out, unsigned* __restrict__ cnt){
  __shared__ __align__(16) char smem[19456];     // union: matmul 18KB / attn 18.9KB
  const int bid = blockIdx.x, t = threadIdx.x;
  const int l = t & 63, wv = t >> 6;
  unsigned* cnt_kc = cnt;            // [4]   matmul units per 2048-j window (==256)
  unsigned* cnt_fs = cnt + 8;        // [128] matmul units per 64-row group (==8)
  unsigned* cnt_cv = cnt + 8 + 128;  // [128] conv blocks per 64-row group (==16)

  if (bid < 1024){
    // ---------- matmul unit: 8 rows of Wh + fs/fd (BK=64 tiles, 18KB LDS)
    float* Ws = (float*)smem;            // [64][64]
    float* hs = (float*)(smem + 16384);  // [8][64]
    const int rb = bid * 8;
    float acc0 = 0.f, acc1 = 0.f;
    for (int p = 0; p < 4; ++p){
      if (p) __syncthreads();
      for (int i = t; i < 1024; i += 256)
        ((float4*)Ws)[i] = ((const float4*)W)[p*1024 + i];
      { int rr = t >> 5, cc = t & 31;
        ((float2*)(hs + rr*64))[cc] =
            *(const float2*)(h + (size_t)(rb+rr)*FIN + p*64 + cc*2); }
      __syncthreads();
      #pragma unroll 8
      for (int k = 0; k < 64; ++k){
        float wval = Ws[k*64 + l];       // lane l = output feature
        acc0 = fmaf(hs[(wv*2+0)*64 + k], wval, acc0);
        acc1 = fmaf(hs[(wv*2+1)*64 + k], wval, acc1);
      }
    }
    const int r0 = rb + wv*2, r1 = r0 + 1;
    float a1 = a[l], a2 = a[64 + l];
    float p0 = acc0*a1, q0 = acc0*a2, p1 = acc1*a1, q1 = acc1*a2;
    #pragma unroll
    for (int m = 1; m < 64; m <<= 1){
      p0 += __shfl_xor(p0, m); q0 += __shfl_xor(q0, m);
      p1 += __shfl_xor(p1, m); q1 += __shfl_xor(q1, m);
    }
    if (l == 0){
      fs[r0] = p0*L2E; fs[r1] = p1*L2E; fd[r0] = q0*L2E; fd[r1] = q1*L2E;
    }
    WhT[(size_t)l*NN + r0] = f2bf(acc0);
    WhT[(size_t)l*NN + r1] = f2bf(acc1);
    __syncthreads();
    if (t == 0){
      __threadfence();                               // publish WhT/fs/fd
      atomicAdd(&cnt_fs[bid >> 3], 1u);
      atomicAdd(&cnt_kc[bid >> 8], 1u);
    }
    return;
  }

  const unsigned u = (unsigned)bid - 1024u;          // 0..2559
  const unsigned r5 = u % 5u, q5 = u / 5u;           // interleave conv:attn = 4:1
  if (r5 < 4u){
    // ---------- converter: 4 adj rows -> bitmask (R0-verified)
    const int cid = (int)(q5*4u + r5);               // 0..2047
    const unsigned rowid = (unsigned)cid*4u + (unsigned)wv;
    const iv4* __restrict__ ap = (const iv4*)(adj + (size_t)rowid*8192u) + l;
    unsigned* __restrict__ mp = mask + rowid*256u;
    iv4 d0 = ap[0*64], d1 = ap[1*64], d2 = ap[2*64], d3 = ap[3*64];
    iv4 d4 = ap[4*64], d5 = ap[5*64], d6 = ap[6*64], d7 = ap[7*64];
    #pragma unroll 1
    for (int i = 0; i < 32; i += 8){
      cv_process(d0, l, mp, i+0); if (i+ 8 < 32) d0 = ap[(i+ 8)*64];
      cv_process(d1, l, mp, i+1); if (i+ 9 < 32) d1 = ap[(i+ 9)*64];
      cv_process(d2, l, mp, i+2); if (i+10 < 32) d2 = ap[(i+10)*64];
      cv_process(d3, l, mp, i+3); if (i+11 < 32) d3 = ap[(i+11)*64];
      cv_process(d4, l, mp, i+4); if (i+12 < 32) d4 = ap[(i+12)*64];
      cv_process(d5, l, mp, i+5); if (i+13 < 32) d5 = ap[(i+13)*64];
      cv_process(d6, l, mp, i+6); if (i+14 < 32) d6 = ap[(i+14)*64];
      cv_process(d7, l, mp, i+7); if (i+15 < 32) d7 = ap[(i+15)*64];
    }
    __syncthreads();
    if (t == 0){
      __threadfence();                               // publish mask rows
      atomicAdd(&cnt_cv[cid >> 4], 1u);              // rows cid*4..+3 in group cid/16
    }
    return;
  }

  // ---------- attention block: 64 i-rows x 2048-j window (R3 body, s<32)
  const int g = (int)(q5 >> 2), kchunk = (int)(q5 & 3u);
  const int row = l & 15, quad = l >> 4;
  const int ibase = g*64 + wv*16;
  const int irow  = ibase + row;
  if (t == 0){
    while (__hip_atomic_load(&cnt_kc[kchunk], __ATOMIC_ACQUIRE, __HIP_MEMORY_SCOPE_AGENT) < 256u)
      __builtin_amdgcn_s_sleep(2);
    while (__hip_atomic_load(&cnt_fs[g], __ATOMIC_ACQUIRE, __HIP_MEMORY_SCOPE_AGENT) < 8u)
      __builtin_amdgcn_s_sleep(2);
    while (__hip_atomic_load(&cnt_cv[g], __ATOMIC_ACQUIRE, __HIP_MEMORY_SCOPE_AGENT) < 16u)
      __builtin_amdgcn_s_sleep(2);
    __threadfence();
  }
  __syncthreads();

  unsigned short* bs0 = (unsigned short*)smem;       // [64][PADK2]
  unsigned short* bs1 = bs0 + 64*PADK2;
  float* fsl0 = (float*)(smem + 18432);              // [64]
  float* fsl1 = fsl0 + 64;

  const float fsrL = fs[irow];
  const float xL   = fsrL + FDBOUND;
  const float mL   = fmaxf(xL, 0.2f*xL);             // row-max upper bound
  const unsigned jbase  = (unsigned)kchunk*2048u;
  const unsigned m_off  = (unsigned)irow*256u + (jbase >> 5);
  const unsigned sg_off = (unsigned)l*8192u + jbase + (unsigned)wv*16u;
  const int      sl_off = l*PADK2 + wv*16;
  const int      qsh    = quad*8;

  f32x4 acc[4];
  #pragma unroll
  for (int nb = 0; nb < 4; ++nb) acc[nb] = (f32x4){0.f,0.f,0.f,0.f};

  { // prologue: stage 0 into buf0; prefetch masks for stages 0,1
    *(short8*)&bs0[sl_off]     = *(const short8*)(WhT + sg_off);
    *(short8*)&bs0[sl_off + 8] = *(const short8*)(WhT + sg_off + 8);
    if (t < 64) fsl0[t] = fd[jbase + t];
  }
  unsigned m0a = mask[m_off + 0] >> qsh, m0b = mask[m_off + 1] >> qsh;
  unsigned m1a = mask[m_off + 2] >> qsh, m1b = mask[m_off + 3] >> qsh;

  float s0 = 0.f, s1 = 0.f;
  short8 nw0, nw1; float nf = 0.f;

  #pragma unroll 1
  for (int s = 0; s < 32; s += 2){
    // ---- even stage: consume buf0/m0, stage s+1 -> buf1
    BAR();
    nw0 = *(const short8*)(WhT + sg_off + (s+1)*64);
    nw1 = *(const short8*)(WhT + sg_off + (s+1)*64 + 8);
    if (t < 64) nf = fd[jbase + (s+1)*64 + t];
    {
      f32x4 fv0 = *(const f32x4*)&fsl0[qsh];
      f32x4 fv1 = *(const f32x4*)&fsl0[qsh + 4];
      short8 w0 = *(const short8*)&bs0[( 0 + row)*PADK2 + qsh];
      short8 w1 = *(const short8*)&bs0[(16 + row)*PADK2 + qsh];
      short8 w2 = *(const short8*)&bs0[(32 + row)*PADK2 + qsh];
      short8 w3 = *(const short8*)&bs0[(48 + row)*PADK2 + qsh];
      attn_math(m0a, fv0, fv1, w0, w1, w2, w3, fsrL, mL, acc, s0, s1);
      fv0 = *(const f32x4*)&fsl0[32 + qsh];
      fv1 = *(const f32x4*)&fsl0[32 + qsh + 4];
      w0 = *(const short8*)&bs0[( 0 + row)*PADK2 + 32 + qsh];
      w1 = *(const short8*)&bs0[(16 + row)*PADK2 + 32 + qsh];
      w2 = *(const short8*)&bs0[(32 + row)*PADK2 + 32 + qsh];
      w3 = *(const short8*)&bs0[(48 + row)*PADK2 + 32 + qsh];
      attn_math(m0b, fv0, fv1, w0, w1, w2, w3, fsrL, mL, acc, s0, s1);
    }
    if (s + 2 < 32){
      m0a = mask[m_off + (s+2)*2]     >> qsh;
      m0b = mask[m_off + (s+2)*2 + 1] >> qsh;
    }
    *(short8*)&bs1[sl_off]     = nw0;
    *(short8*)&bs1[sl_off + 8] = nw1;
    if (t < 64) fsl1[t] = nf;

    // ---- odd stage: consume buf1/m1, stage s+2 -> buf0
    BAR();
    if (s + 2 < 32){
      nw0 = *(const short8*)(WhT + sg_off + (s+2)*64);
      nw1 = *(const short8*)(WhT + sg_off + (s+2)*64 + 8);
      if (t < 64) nf = fd[jbase + (s+2)*64 + t];
    }
    {
      f32x4 fv0 = *(const f32x4*)&fsl1[qsh];
      f32x4 fv1 = *(const f32x4*)&fsl1[qsh + 4];
      short8 w0 = *(const short8*)&bs1[( 0 + row)*PADK2 + qsh];
      short8 w1 = *(const short8*)&bs1[(16 + row)*PADK2 + qsh];
      short8 w2 = *(const short8*)&bs1[(32 + row)*PADK2 + qsh];
      short8 w3 = *(const short8*)&bs1[(48 + row)*PADK2 + qsh];
      attn_math(m1a, fv0, fv1, w0, w1, w2, w3, fsrL, mL, acc, s0, s1);
      fv0 = *(const f32x4*)&fsl1[32 + qsh];
      fv1 = *(const f32x4*)&fsl1[32 + qsh + 4];
      w0 = *(const short8*)&bs1[( 0 + row)*PADK2 + 32 + qsh];
      w1 = *(const short8*)&bs1[(16 + row)*PADK2 + 32 + qsh];
      w2 = *(const short8*)&bs1[(32 + row)*PADK2 + 32 + qsh];
      w3 = *(const short8*)&bs1[(48 + row)*PADK2 + 32 + qsh];
      attn_math(m1b, fv0, fv1, w0, w1, w2, w3, fsrL, mL, acc, s0, s1);
    }
    if (s + 3 < 32){
      m1a = mask[m_off + (s+3)*2]     >> qsh;
      m1b = mask[m_off + (s+3)*2 + 1] >> qsh;
    }
    if (s + 2 < 32){
      *(short8*)&bs0[sl_off]     = nw0;
      *(short8*)&bs0[sl_off + 8] = nw1;
      if (t < 64) fsl0[t] = nf;
    }
  }

  float sacc = s0 + s1;
  sacc += __shfl_xor(sacc, 16);
  sacc += __shfl_xor(sacc, 32);
  if (l < 16) s_out[kchunk*NN + ibase + l] = sacc;
  float* op = acc_out + ((size_t)kchunk*NN + ibase)*FOUT;
  #pragma unroll
  for (int nb = 0; nb < 4; ++nb)
    #pragma unroll
    for (int r = 0; r < 4; ++r)
      op[(quad*4 + r)*FOUT + nb*16 + row] = acc[nb][r];
}

// ---- k_out: combine 4 split-K partials, normalize, ELU (float4/thread).
__global__ __launch_bounds__(256) void k_out(const float* __restrict__ acc,
    const float* __restrict__ s, float* __restrict__ out){
  const int idx4 = blockIdx.x*256 + threadIdx.x;   // 131072 total (x4 floats)
  const int i = idx4 >> 4;                         // 16 float4 per row
  float4 num = make_float4(0.f,0.f,0.f,0.f);
  float den = 0.f;
  #pragma unroll
  for (int ks = 0; ks < 4; ++ks){
    float4 v = ((const float4*)acc)[idx4 + ks*(NN*FOUT/4)];
    num.x += v.x; num.y += v.y; num.z += v.z; num.w += v.w;
    den += s[i + ks*NN];
  }
  const float rd = 1.0f / den;
  float4 o;
  float x;
  x = num.x*rd; o.x = (x > 0.f) ? x : (__expf(x) - 1.0f);
  x = num.y*rd; o.y = (x > 0.f) ? x : (__expf(x) - 1.0f);
  x = num.z*rd; o.z = (x > 0.f) ? x : (__expf(x) - 1.0f);
  x = num.w*rd; o.w = (x > 0.f) ? x : (__expf(x) - 1.0f);
  ((float4*)out)[idx4] = o;
}

extern "C" void kernel_launch(void* const* d_in, const int* in_sizes, int n_in,
                              void* d_out, int out_size, void* d_ws, size_t ws_size,
                              hipStream_t stream){
  const float* h   = (const float*)d_in[0];
  const int*   adj = (const int*)d_in[1];
  const float* W   = (const float*)d_in[2];
  const float* a   = (const float*)d_in[3];
  char* ws = (char*)d_ws;
  // ws: [0,1M) WhT | 1M fs | +32K fd | [2M,10M) acc x4 | [20M,+128K) s x4 |
  //     [48M,56M) mask | 57M counters (4KB)
  unsigned short* WhT = (unsigned short*)ws;
  float*    fs     = (float*)(ws + (1u<<20));
  float*    fd     = (float*)(ws + (1u<<20) + 32768);
  float*    acc    = (float*)(ws + (2u<<20));
  float*    s_ws   = (float*)(ws + (20u<<20));
  unsigned* mask   = (unsigned*)(ws + (48u<<20));
  unsigned* cnt    = (unsigned*)(ws + (57u<<20));

  (void)hipMemsetAsync(cnt, 0, 4096, stream);
  k_mega<<<3584, 256, 0, stream>>>(h, W, a, adj, WhT, fs, fd, mask, acc, s_ws, cnt);
  k_out<<<512, 256, 0, stream>>>(acc, s_ws, (float*)d_out);
}

// Round 9
// 432.435 us; speedup vs baseline: 1.5579x; 1.5579x over previous
//
#include <hip/hip_runtime.h>
#include <hip/hip_bf16.h>

#define NN 8192
#define FIN 256
#define FOUT 64
#define L2E 1.4426950408889634f
#define PADK2 72      // LDS k-stride in shorts (64 data + 8 pad; R3-verified)
#define FDBOUND 64.0f // safe upper bound on max_j fd[j] (verified by R8 pass:
                      // softmax offset cancels in num/den; exp2 args stay in range)

typedef __attribute__((ext_vector_type(8))) short short8;
typedef __attribute__((ext_vector_type(4))) float f32x4;
typedef __attribute__((ext_vector_type(4))) int   iv4;

// Barrier with LDS-only drain: leaves vmcnt (global prefetch) in flight.
#define BAR() do { \
  __asm__ __volatile__("s_waitcnt lgkmcnt(0)" ::: "memory"); \
  __builtin_amdgcn_s_barrier(); \
  __asm__ __volatile__("" ::: "memory"); \
} while (0)

__device__ __forceinline__ unsigned short f2bf(float x){
  unsigned u = __float_as_uint(x);
  u += 0x7FFFu + ((u >> 16) & 1u);      // RTNE
  return (unsigned short)(u >> 16);
}

// ---- k_pm: matmul-only prep (R1-verified body; converter ELIMINATED —
// k_attn now stages+packs raw adj inside its own pipeline).
__global__ __launch_bounds__(256) void k_pm(const float* __restrict__ h,
    const float* __restrict__ W, const float* __restrict__ a,
    unsigned short* __restrict__ WhT, float* __restrict__ fs,
    float* __restrict__ fd){
  const int t = threadIdx.x;
  const int l = t & 63, wv = t >> 6;
  __shared__ float Ws[128*64];   // 32 KB: half of W (k-tiled)
  __shared__ float hs[8][128];
  const int rb = blockIdx.x * 8;          // 8 rows per block, 2 per wave
  float acc0 = 0.f, acc1 = 0.f;
  for (int half = 0; half < 2; ++half){
    if (half) __syncthreads();
    for (int i = t; i < 2048; i += 256)
      ((float4*)Ws)[i] = ((const float4*)W)[half*2048 + i];
    {
      int rr = t >> 5, cc = t & 31;
      ((float4*)&hs[rr][0])[cc] =
          *(const float4*)(h + (size_t)(rb+rr)*FIN + half*128 + cc*4);
    }
    __syncthreads();
    #pragma unroll 8
    for (int k = 0; k < 128; ++k){
      float wval = Ws[k*64 + l];           // lane l = output feature
      acc0 = fmaf(hs[wv*2+0][k], wval, acc0);
      acc1 = fmaf(hs[wv*2+1][k], wval, acc1);
    }
  }
  const int r0 = rb + wv*2, r1 = r0 + 1;
  float a1 = a[l], a2 = a[64 + l];
  float p0 = acc0*a1, q0 = acc0*a2, p1 = acc1*a1, q1 = acc1*a2;
  #pragma unroll
  for (int m = 1; m < 64; m <<= 1){
    p0 += __shfl_xor(p0, m); q0 += __shfl_xor(q0, m);
    p1 += __shfl_xor(p1, m); q1 += __shfl_xor(q1, m);
  }
  if (l == 0){
    fs[r0] = p0*L2E; fs[r1] = p1*L2E; fd[r0] = q0*L2E; fd[r1] = q1*L2E;
  }
  WhT[(size_t)l*NN + r0] = f2bf(acc0);
  WhT[(size_t)l*NN + r1] = f2bf(acc1);
}

// Pack 16 consecutive adj ints (4 iv4) to 16 gate bits (bit k <-> int k).
__device__ __forceinline__ unsigned short pack16(iv4 a, iv4 b, iv4 c, iv4 d){
  unsigned n0 = (unsigned)(a.x!=0) | ((unsigned)(a.y!=0)<<1)
              | ((unsigned)(a.z!=0)<<2) | ((unsigned)(a.w!=0)<<3);
  unsigned n1 = (unsigned)(b.x!=0) | ((unsigned)(b.y!=0)<<1)
              | ((unsigned)(b.z!=0)<<2) | ((unsigned)(b.w!=0)<<3);
  unsigned n2 = (unsigned)(c.x!=0) | ((unsigned)(c.y!=0)<<1)
              | ((unsigned)(c.z!=0)<<2) | ((unsigned)(c.w!=0)<<3);
  unsigned n3 = (unsigned)(d.x!=0) | ((unsigned)(d.y!=0)<<1)
              | ((unsigned)(d.z!=0)<<2) | ((unsigned)(d.w!=0)<<3);
  return (unsigned short)(n0 | (n1<<4) | (n2<<8) | (n3<<12));
}

__device__ __forceinline__ void attn_math(unsigned mbits, f32x4 fv0, f32x4 fv1,
    short8 w0, short8 w1, short8 w2, short8 w3,
    float fsrL, float mL, f32x4* acc, float& s0, float& s1){
  const float fv[8] = {fv0[0],fv0[1],fv0[2],fv0[3], fv1[0],fv1[1],fv1[2],fv1[3]};
  float w[8];
  #pragma unroll
  for (int j = 0; j < 8; ++j){
    float x  = fsrL + fv[j];                      // log2 domain
    float tt = fmaxf(x, 0.2f*x);                  // leaky_relu (scale-invariant)
    float e  = __builtin_amdgcn_exp2f(tt - mL);   // v_exp_f32
    w[j] = (mbits & (1u << j)) ? e : 0.0f;        // adj gate bit
  }
  s0 += (w[0]+w[2]) + (w[4]+w[6]);
  s1 += (w[1]+w[3]) + (w[5]+w[7]);
  short8 af;
  __hip_bfloat162* afp = (__hip_bfloat162*)&af;
  #pragma unroll
  for (int j = 0; j < 4; ++j)
    afp[j] = __float22bfloat162_rn(make_float2(w[2*j], w[2*j+1]));  // v_cvt_pk_bf16_f32
  acc[0] = __builtin_amdgcn_mfma_f32_16x16x32_bf16(af, w0, acc[0], 0,0,0);
  acc[1] = __builtin_amdgcn_mfma_f32_16x16x32_bf16(af, w1, acc[1], 0,0,0);
  acc[2] = __builtin_amdgcn_mfma_f32_16x16x32_bf16(af, w2, acc[2], 0,0,0);
  acc[3] = __builtin_amdgcn_mfma_f32_16x16x32_bf16(af, w3, acc[3], 0,0,0);
}

// ---- k_attn: R3's verified 64-i x 1024-j / 16-stage schedule, with adj
// staged RAW inside the same pipeline: 4x dwordx4/thread issued WITH the
// WhT staging loads (same issue point, same stage-bottom vmcnt wait ->
// zero added latency exposure), packed in-register to a 16-bit gate word,
// one ushort -> LDS. Converter kernel + 8MB mask round-trip eliminated.
// Verified layouts (m89/m120): A[m=lane&15][k=(lane>>4)*8+j],
// B[k=(lane>>4)*8+j][n=lane&15], C col=lane&15 row=(lane>>4)*4+reg.
__global__ __launch_bounds__(256, 3) void k_attn(const int* __restrict__ adj,
    const unsigned short* __restrict__ WhT, const float* __restrict__ fs,
    const float* __restrict__ fd, float* __restrict__ acc_out,
    float* __restrict__ s_out){
  __shared__ unsigned short bslab[2][64*PADK2];  // [buf][feature][k]  18 KB
  __shared__ float fslab[2][64];
  __shared__ unsigned short mlds[2][64][4];      // [buf][i-row][16j-word]  1 KB
  const int t = threadIdx.x, l = t & 63, wv = t >> 6;
  const int g = blockIdx.x & 127;        // 128 groups of 64 i-rows
  const int kchunk = blockIdx.x >> 7;    // 8 k-splits of 1024 j
  const int row = l & 15, quad = l >> 4;
  const int ibase = g*64 + wv*16;
  const int irow  = ibase + row;
  const float fsrL  = fs[irow];
  const float xL    = fsrL + FDBOUND;
  const float mL    = fmaxf(xL, 0.2f*xL);  // row-max upper bound (leaky monotone)

  const unsigned jbase = (unsigned)kchunk*1024u;
  const unsigned sg_off = (unsigned)l*8192u + jbase + (unsigned)wv*16u;
  const int      sl_off = l*PADK2 + wv*16;
  const int      qsh    = quad*8;
  // adj staging role: thread t stages local row rr = t>>2, j-quarter qq = t&3
  const int rr = t >> 2, qq = t & 3;
  const iv4* __restrict__ ar =
      (const iv4*)(adj + (size_t)(g*64 + rr)*8192u + jbase) + qq*4;
  // stage s -> ar[s*16 + {0..3}]  (64 B/thread, 256-B contiguous per 4-thread row)
  const int lr = wv*16 + row;            // consumer local row
  const int mw = quad >> 1, msh = (quad & 1)*8;

  f32x4 acc[4];
  #pragma unroll
  for (int nb = 0; nb < 4; ++nb) acc[nb] = (f32x4){0.f,0.f,0.f,0.f};

  // prologue: stage 0 (WhT + fd + adj gates) into buf 0
  {
    *(short8*)&bslab[0][sl_off]     = *(const short8*)(WhT + sg_off);
    *(short8*)&bslab[0][sl_off + 8] = *(const short8*)(WhT + sg_off + 8);
    if (t < 64) fslab[0][t] = fd[jbase + t];
    iv4 b0 = ar[0], b1 = ar[1], b2 = ar[2], b3 = ar[3];
    mlds[0][rr][qq] = pack16(b0, b1, b2, b3);
  }

  float s0 = 0.f, s1 = 0.f;
  short8 nw0, nw1; float nf = 0.f;
  iv4 a0, a1, a2, a3;

  #pragma unroll 1
  for (int s = 0; s < 16; s += 2){
    // ---- even stage: consume buf0, stage s+1 -> buf1
    BAR();
    nw0 = *(const short8*)(WhT + sg_off + (s+1)*64);
    nw1 = *(const short8*)(WhT + sg_off + (s+1)*64 + 8);
    if (t < 64) nf = fd[jbase + (s+1)*64 + t];
    a0 = ar[(s+1)*16 + 0]; a1 = ar[(s+1)*16 + 1];
    a2 = ar[(s+1)*16 + 2]; a3 = ar[(s+1)*16 + 3];
    {
      unsigned m0a = mlds[0][lr][mw]     >> msh;
      unsigned m0b = mlds[0][lr][2 + mw] >> msh;
      f32x4 fv0 = *(const f32x4*)&fslab[0][qsh];
      f32x4 fv1 = *(const f32x4*)&fslab[0][qsh + 4];
      short8 w0 = *(const short8*)&bslab[0][( 0 + row)*PADK2 + qsh];
      short8 w1 = *(const short8*)&bslab[0][(16 + row)*PADK2 + qsh];
      short8 w2 = *(const short8*)&bslab[0][(32 + row)*PADK2 + qsh];
      short8 w3 = *(const short8*)&bslab[0][(48 + row)*PADK2 + qsh];
      attn_math(m0a, fv0, fv1, w0, w1, w2, w3, fsrL, mL, acc, s0, s1);
      fv0 = *(const f32x4*)&fslab[0][32 + qsh];
      fv1 = *(const f32x4*)&fslab[0][32 + qsh + 4];
      w0 = *(const short8*)&bslab[0][( 0 + row)*PADK2 + 32 + qsh];
      w1 = *(const short8*)&bslab[0][(16 + row)*PADK2 + 32 + qsh];
      w2 = *(const short8*)&bslab[0][(32 + row)*PADK2 + 32 + qsh];
      w3 = *(const short8*)&bslab[0][(48 + row)*PADK2 + 32 + qsh];
      attn_math(m0b, fv0, fv1, w0, w1, w2, w3, fsrL, mL, acc, s0, s1);
    }
    *(short8*)&bslab[1][sl_off]     = nw0;
    *(short8*)&bslab[1][sl_off + 8] = nw1;
    if (t < 64) fslab[1][t] = nf;
    mlds[1][rr][qq] = pack16(a0, a1, a2, a3);

    // ---- odd stage: consume buf1, stage s+2 -> buf0
    BAR();
    if (s + 2 < 16){
      nw0 = *(const short8*)(WhT + sg_off + (s+2)*64);
      nw1 = *(const short8*)(WhT + sg_off + (s+2)*64 + 8);
      if (t < 64) nf = fd[jbase + (s+2)*64 + t];
      a0 = ar[(s+2)*16 + 0]; a1 = ar[(s+2)*16 + 1];
      a2 = ar[(s+2)*16 + 2]; a3 = ar[(s+2)*16 + 3];
    }
    {
      unsigned m1a = mlds[1][lr][mw]     >> msh;
      unsigned m1b = mlds[1][lr][2 + mw] >> msh;
      f32x4 fv0 = *(const f32x4*)&fslab[1][qsh];
      f32x4 fv1 = *(const f32x4*)&fslab[1][qsh + 4];
      short8 w0 = *(const short8*)&bslab[1][( 0 + row)*PADK2 + qsh];
      short8 w1 = *(const short8*)&bslab[1][(16 + row)*PADK2 + qsh];
      short8 w2 = *(const short8*)&bslab[1][(32 + row)*PADK2 + qsh];
      short8 w3 = *(const short8*)&bslab[1][(48 + row)*PADK2 + qsh];
      attn_math(m1a, fv0, fv1, w0, w1, w2, w3, fsrL, mL, acc, s0, s1);
      fv0 = *(const f32x4*)&fslab[1][32 + qsh];
      fv1 = *(const f32x4*)&fslab[1][32 + qsh + 4];
      w0 = *(const short8*)&bslab[1][( 0 + row)*PADK2 + 32 + qsh];
      w1 = *(const short8*)&bslab[1][(16 + row)*PADK2 + 32 + qsh];
      w2 = *(const short8*)&bslab[1][(32 + row)*PADK2 + 32 + qsh];
      w3 = *(const short8*)&bslab[1][(48 + row)*PADK2 + 32 + qsh];
      attn_math(m1b, fv0, fv1, w0, w1, w2, w3, fsrL, mL, acc, s0, s1);
    }
    if (s + 2 < 16){
      *(short8*)&bslab[0][sl_off]     = nw0;
      *(short8*)&bslab[0][sl_off + 8] = nw1;
      if (t < 64) fslab[0][t] = nf;
      mlds[0][rr][qq] = pack16(a0, a1, a2, a3);
    }
  }

  float sacc = s0 + s1;
  sacc += __shfl_xor(sacc, 16);
  sacc += __shfl_xor(sacc, 32);
  if (l < 16) s_out[kchunk*NN + ibase + l] = sacc;
  float* op = acc_out + ((size_t)kchunk*NN + ibase)*FOUT;
  #pragma unroll
  for (int nb = 0; nb < 4; ++nb)
    #pragma unroll
    for (int r = 0; r < 4; ++r)
      op[(quad*4 + r)*FOUT + nb*16 + row] = acc[nb][r];
}

// ---- k_out: combine 8 split-K partials, normalize, ELU (float4/thread).
__global__ __launch_bounds__(256) void k_out(const float* __restrict__ acc,
    const float* __restrict__ s, float* __restrict__ out){
  const int idx4 = blockIdx.x*256 + threadIdx.x;   // 131072 total (x4 floats)
  const int i = idx4 >> 4;                         // 16 float4 per row
  float4 num = make_float4(0.f,0.f,0.f,0.f);
  float den = 0.f;
  #pragma unroll
  for (int ks = 0; ks < 8; ++ks){
    float4 v = ((const float4*)acc)[idx4 + ks*(NN*FOUT/4)];
    num.x += v.x; num.y += v.y; num.z += v.z; num.w += v.w;
    den += s[i + ks*NN];
  }
  const float rd = 1.0f / den;
  float4 o;
  float x;
  x = num.x*rd; o.x = (x > 0.f) ? x : (__expf(x) - 1.0f);
  x = num.y*rd; o.y = (x > 0.f) ? x : (__expf(x) - 1.0f);
  x = num.z*rd; o.z = (x > 0.f) ? x : (__expf(x) - 1.0f);
  x = num.w*rd; o.w = (x > 0.f) ? x : (__expf(x) - 1.0f);
  ((float4*)out)[idx4] = o;
}

extern "C" void kernel_launch(void* const* d_in, const int* in_sizes, int n_in,
                              void* d_out, int out_size, void* d_ws, size_t ws_size,
                              hipStream_t stream){
  const float* h   = (const float*)d_in[0];
  const int*   adj = (const int*)d_in[1];
  const float* W   = (const float*)d_in[2];
  const float* a   = (const float*)d_in[3];
  char* ws = (char*)d_ws;
  // ws: [0,1M) WhT | 1M fs | +32K fd | [2M,18M) acc x8 | [20M,+256K) s x8
  unsigned short* WhT = (unsigned short*)ws;
  float*    fs     = (float*)(ws + (1u<<20));
  float*    fd     = (float*)(ws + (1u<<20) + 32768);
  float*    acc    = (float*)(ws + (2u<<20));
  float*    s_ws   = (float*)(ws + (20u<<20));

  k_pm<<<1024, 256, 0, stream>>>(h, W, a, WhT, fs, fd);
  k_attn<<<1024, 256, 0, stream>>>(adj, WhT, fs, fd, acc, s_ws);
  k_out<<<512, 256, 0, stream>>>(acc, s_ws, (float*)d_out);
}